// Round 2
// baseline (45178.964 us; speedup 1.0000x reference)
//
#include <hip/hip_runtime.h>
#include <math.h>

#define NPTS   1000000
#define TILE   64
#define NBLK   (NPTS / TILE)     // 15625
#define NSLOTS 256               // f64 partial-sum slots in ws

__device__ __forceinline__ unsigned rotl32(unsigned v, int r) {
    return (v << r) | (v >> (32 - r));
}

// ---- JAX partitionable threefry2x32, key=(0,42) ----
// Per element flat index i: cipher inputs (hi32(i), lo32(i)) = (0, i);
// output bits = x0_out ^ x1_out.  Then uniform(-1+ulp,1) + XLA ErfInv32.
__device__ __forceinline__ float jax_normal_f(unsigned idx) {
    const unsigned ks0 = 0u, ks1 = 42u, ks2 = (0u ^ 42u ^ 0x1BD11BDAu);
    unsigned x0 = 0u + ks0;      // counts1 = hi32(index) = 0 for idx < 2^32
    unsigned x1 = idx + ks1;     // counts2 = lo32(index)
#define TFR(r) { x0 += x1; x1 = rotl32(x1, (r)); x1 ^= x0; }
    TFR(13) TFR(15) TFR(26) TFR(6)  x0 += ks1; x1 += ks2 + 1u;
    TFR(17) TFR(29) TFR(16) TFR(24) x0 += ks2; x1 += ks0 + 2u;
    TFR(13) TFR(15) TFR(26) TFR(6)  x0 += ks0; x1 += ks1 + 3u;
    TFR(17) TFR(29) TFR(16) TFR(24) x0 += ks1; x1 += ks2 + 4u;
    TFR(13) TFR(15) TFR(26) TFR(6)  x0 += ks2; x1 += ks0 + 5u;
#undef TFR
    unsigned bits = x0 ^ x1;
    // uniform: f in [0,1); u = f*(hi-lo) + lo, hi-lo folds to 2.0f exactly
    float f = __uint_as_float((bits >> 9) | 0x3f800000u) - 1.0f;
    float u = f * 2.0f + (-0.99999994f);
    u = fmaxf(-0.99999994f, u);
    // XLA ErfInv32
    float w = -log1pf(-u * u);
    float p;
    if (w < 5.0f) {
        w -= 2.5f;
        p = 2.81022636e-08f;
        p = fmaf(p, w, 3.43273939e-07f);
        p = fmaf(p, w, -3.5233877e-06f);
        p = fmaf(p, w, -4.39150654e-06f);
        p = fmaf(p, w, 0.00021858087f);
        p = fmaf(p, w, -0.00125372503f);
        p = fmaf(p, w, -0.00417768164f);
        p = fmaf(p, w, 0.246640727f);
        p = fmaf(p, w, 1.50140941f);
    } else {
        w = sqrtf(w) - 3.0f;
        p = -0.000200214257f;
        p = fmaf(p, w, 0.000100950558f);
        p = fmaf(p, w, 0.00134934322f);
        p = fmaf(p, w, -0.00367342844f);
        p = fmaf(p, w, 0.00573950773f);
        p = fmaf(p, w, -0.0076224613f);
        p = fmaf(p, w, 0.00943887047f);
        p = fmaf(p, w, 1.00167406f);
        p = fmaf(p, w, 2.83297682f);
    }
    return 1.41421356f * (p * u);   // sqrt(2) * erfinv(u)
}

// ---- XLA f32 tanh (rational 7/4 with clamp; passthrough for tiny x) ----
__device__ __forceinline__ float xla_tanh(float x) {
    float ax = fabsf(x);
    float xc = fminf(fmaxf(x, -7.90531110763549805f), 7.90531110763549805f);
    float x2 = xc * xc;
    float np_ = -2.76076847742355e-16f;
    np_ = fmaf(np_, x2, 2.00018790482477e-13f);
    np_ = fmaf(np_, x2, -8.60467152213735e-11f);
    np_ = fmaf(np_, x2, 5.12229709037114e-08f);
    np_ = fmaf(np_, x2, 1.48572235717979e-05f);
    np_ = fmaf(np_, x2, 6.37261928875436e-04f);
    np_ = fmaf(np_, x2, 4.89352455891786e-03f);
    float num = xc * np_;
    float dp_ = 1.19825839466702e-06f;
    dp_ = fmaf(dp_, x2, 1.18534705686654e-04f);
    dp_ = fmaf(dp_, x2, 2.26843463243900e-03f);
    dp_ = fmaf(dp_, x2, 4.89352518554385e-03f);
    float r = num / dp_;
    return (ax < 0.0004f) ? x : r;
}

// ---- Fourier features into LDS buf[ i*TILE + lane ], rows 0..129 ----
__device__ __forceinline__ void compute_feats(const float* __restrict__ inp,
                                              const float* __restrict__ fB,
                                              float* buf, int lane, int wave, int base) {
    if (wave == 0) {
        float2 xy = reinterpret_cast<const float2*>(inp)[base + lane];
        buf[0 * TILE + lane] = xy.x;
        buf[1 * TILE + lane] = xy.y;
    }
    __syncthreads();
    float x0 = buf[0 * TILE + lane];
    float x1 = buf[1 * TILE + lane];
#pragma unroll
    for (int q = 0; q < 16; ++q) {
        int j = wave * 16 + q;                       // wave-uniform j
        float dot = x0 * fB[j] + x1 * fB[64 + j];    // mirror XLA mul/add order
        float pr = 6.2831855f * dot;
        buf[(2 + j) * TILE + lane]  = sinf(pr);
        buf[(66 + j) * TILE + lane] = cosf(pr);
    }
    __syncthreads();
}

// ---- layer-0 accumulator: 8 outputs (o0..o0+7) for this lane's point ----
__device__ __forceinline__ void layer0_acc(const float* __restrict__ W0,
                                           const float* __restrict__ b0,
                                           const float* fb, int lane, int o0,
                                           float acc[8]) {
#pragma unroll
    for (int k = 0; k < 8; ++k) acc[k] = b0[o0 + k];
    for (int i4 = 0; i4 < 32; ++i4) {
        float4 w[8];
#pragma unroll
        for (int k = 0; k < 8; ++k)
            w[k] = *reinterpret_cast<const float4*>(W0 + (o0 + k) * 130 + i4 * 4);
#pragma unroll
        for (int j = 0; j < 4; ++j) {
            float hv = fb[(i4 * 4 + j) * TILE + lane];
#pragma unroll
            for (int k = 0; k < 8; ++k) {
                float wv = (j == 0) ? w[k].x : (j == 1) ? w[k].y : (j == 2) ? w[k].z : w[k].w;
                acc[k] = fmaf(hv, wv, acc[k]);
            }
        }
    }
    float h0 = fb[128 * TILE + lane], h1 = fb[129 * TILE + lane];
#pragma unroll
    for (int k = 0; k < 8; ++k) {
        float2 wt = *reinterpret_cast<const float2*>(W0 + (o0 + k) * 130 + 128);
        acc[k] = fmaf(h0, wt.x, acc[k]);
        acc[k] = fmaf(h1, wt.y, acc[k]);
    }
}

// ---- generic 128->128 layer with tanh ----
__device__ __forceinline__ void mid_layer(const float* __restrict__ W,
                                          const float* __restrict__ b,
                                          const float* bin, float* bout,
                                          int lane, int wave) {
#pragma unroll
    for (int s = 0; s < 4; ++s) {
        int o0 = s * 32 + wave * 8;
        float acc[8];
#pragma unroll
        for (int k = 0; k < 8; ++k) acc[k] = b[o0 + k];
        for (int i4 = 0; i4 < 32; ++i4) {
            float4 w[8];
#pragma unroll
            for (int k = 0; k < 8; ++k)
                w[k] = *reinterpret_cast<const float4*>(W + (o0 + k) * 128 + i4 * 4);
#pragma unroll
            for (int j = 0; j < 4; ++j) {
                float hv = bin[(i4 * 4 + j) * TILE + lane];
#pragma unroll
                for (int k = 0; k < 8; ++k) {
                    float wv = (j == 0) ? w[k].x : (j == 1) ? w[k].y : (j == 2) ? w[k].z : w[k].w;
                    acc[k] = fmaf(hv, wv, acc[k]);
                }
            }
        }
#pragma unroll
        for (int k = 0; k < 8; ++k)
            bout[(o0 + k) * TILE + lane] = xla_tanh(acc[k]);
    }
}

// ================= pass A: sum of y^2 over all N*128 layer-0 outputs ========
__global__ __launch_bounds__(256) void pass_a(const float* __restrict__ inp,
                                              const float* __restrict__ fB,
                                              const float* __restrict__ W0,
                                              const float* __restrict__ b0,
                                              double* __restrict__ ssq) {
    __shared__ float fb[130 * TILE];
    __shared__ double red[256];
    int t = threadIdx.x;
    int lane = t & 63, wave = t >> 6;
    int base = blockIdx.x * TILE;

    compute_feats(inp, fB, fb, lane, wave, base);

    float ss = 0.f;
#pragma unroll
    for (int s = 0; s < 4; ++s) {
        int o0 = s * 32 + wave * 8;
        float acc[8];
        layer0_acc(W0, b0, fb, lane, o0, acc);
#pragma unroll
        for (int k = 0; k < 8; ++k) ss = fmaf(acc[k], acc[k], ss);
    }
    red[t] = (double)ss;
    __syncthreads();
    for (int off = 128; off > 0; off >>= 1) {
        if (t < off) red[t] += red[t + off];
        __syncthreads();
    }
    if (t == 0) atomicAdd(&ssq[blockIdx.x & (NSLOTS - 1)], red[0]);
}

// ================= std finalize ============================================
__global__ void finalize_std(const double* __restrict__ ssq, float* __restrict__ stdp) {
    double s = 0.0;
    for (int i = 0; i < NSLOTS; ++i) s += ssq[i];
    float power = (float)(s / 128000000.0);
    float v = 0.f;
    if (isfinite(power) && power > 1.1920929e-07f) v = sqrtf(power / 1000.0f);
    *stdp = v;
}

// ================= pass B: full fused forward ==============================
__global__ __launch_bounds__(256) void pass_b(const float* __restrict__ inp,
                                              const float* __restrict__ fB,
                                              const float* __restrict__ W0, const float* __restrict__ b0,
                                              const float* __restrict__ W1, const float* __restrict__ b1,
                                              const float* __restrict__ W2, const float* __restrict__ b2,
                                              const float* __restrict__ W3, const float* __restrict__ b3,
                                              const float* __restrict__ W4, const float* __restrict__ b4,
                                              const float* __restrict__ stdp,
                                              float* __restrict__ out) {
    __shared__ float bufA[130 * TILE];
    __shared__ float bufB[128 * TILE];
    int t = threadIdx.x;
    int lane = t & 63, wave = t >> 6;
    int base = blockIdx.x * TILE;

    compute_feats(inp, fB, bufA, lane, wave, base);
    float stdv = *stdp;

    // layer 0: bufA(130) -> bufB(128), STE noise + tanh
    unsigned n = (unsigned)(base + lane);
#pragma unroll
    for (int s = 0; s < 4; ++s) {
        int o0 = s * 32 + wave * 8;
        float acc[8];
        layer0_acc(W0, b0, bufA, lane, o0, acc);
#pragma unroll
        for (int k = 0; k < 8; ++k) {
            float y   = acc[k];
            float nz  = jax_normal_f(n * 128u + (unsigned)(o0 + k));
            float yhw = y + nz * stdv;          // y + normal*std (mul then add)
            float h   = (yhw + y) - y;          // forward value of the STE expr
            bufB[(o0 + k) * TILE + lane] = xla_tanh(h);
        }
    }
    __syncthreads();

    mid_layer(W1, b1, bufB, bufA, lane, wave);
    __syncthreads();
    mid_layer(W2, b2, bufA, bufB, lane, wave);
    __syncthreads();
    mid_layer(W3, b3, bufB, bufA, lane, wave);
    __syncthreads();

    // layer 4: 128 -> 2, wave 0 only
    if (wave == 0) {
        float a0 = b4[0], a1 = b4[1];
        for (int i = 0; i < 128; ++i) {
            float hv = bufA[i * TILE + lane];
            a0 = fmaf(hv, W4[i], a0);
            a1 = fmaf(hv, W4[128 + i], a1);
        }
        reinterpret_cast<float2*>(out)[base + lane] = make_float2(a0, a1);
    }
}

extern "C" void kernel_launch(void* const* d_in, const int* in_sizes, int n_in,
                              void* d_out, int out_size, void* d_ws, size_t ws_size,
                              hipStream_t stream) {
    const float* inp = (const float*)d_in[0];
    const float* fB  = (const float*)d_in[1];
    const float* W0  = (const float*)d_in[2];
    const float* b0  = (const float*)d_in[3];
    const float* W1  = (const float*)d_in[4];
    const float* b1  = (const float*)d_in[5];
    const float* W2  = (const float*)d_in[6];
    const float* b2  = (const float*)d_in[7];
    const float* W3  = (const float*)d_in[8];
    const float* b3  = (const float*)d_in[9];
    const float* W4  = (const float*)d_in[10];
    const float* b4  = (const float*)d_in[11];
    float*  out  = (float*)d_out;
    double* ssq  = (double*)d_ws;                        // NSLOTS doubles
    float*  stdp = (float*)((char*)d_ws + NSLOTS * 8);   // then 1 float

    hipMemsetAsync(d_ws, 0, NSLOTS * 8, stream);
    pass_a<<<NBLK, 256, 0, stream>>>(inp, fB, W0, b0, ssq);
    finalize_std<<<1, 1, 0, stream>>>(ssq, stdp);
    pass_b<<<NBLK, 256, 0, stream>>>(inp, fB, W0, b0, W1, b1, W2, b2, W3, b3,
                                     W4, b4, stdp, out);
}

// Round 3
// 7544.962 us; speedup vs baseline: 5.9880x; 5.9880x over previous
//
#include <hip/hip_runtime.h>
#include <math.h>

#define NPTS   1000000
#define TILE   64
#define NBLK   (NPTS / TILE)     // 15625
#define NSLOTS 256               // f64 partial-sum slots in ws

__device__ __forceinline__ unsigned rotl32(unsigned v, int r) {
    return (v << r) | (v >> (32 - r));
}

// ---- JAX partitionable threefry2x32, key=(0,42) ----
// bits = x0_out ^ x1_out with cipher inputs (0, idx); uniform(-1+ulp,1); XLA ErfInv32.
__device__ __forceinline__ float jax_normal_f(unsigned idx) {
    const unsigned ks0 = 0u, ks1 = 42u, ks2 = (0u ^ 42u ^ 0x1BD11BDAu);
    unsigned x0 = 0u + ks0;
    unsigned x1 = idx + ks1;
#define TFR(r) { x0 += x1; x1 = rotl32(x1, (r)); x1 ^= x0; }
    TFR(13) TFR(15) TFR(26) TFR(6)  x0 += ks1; x1 += ks2 + 1u;
    TFR(17) TFR(29) TFR(16) TFR(24) x0 += ks2; x1 += ks0 + 2u;
    TFR(13) TFR(15) TFR(26) TFR(6)  x0 += ks0; x1 += ks1 + 3u;
    TFR(17) TFR(29) TFR(16) TFR(24) x0 += ks1; x1 += ks2 + 4u;
    TFR(13) TFR(15) TFR(26) TFR(6)  x0 += ks2; x1 += ks0 + 5u;
#undef TFR
    unsigned bits = x0 ^ x1;
    float f = __uint_as_float((bits >> 9) | 0x3f800000u) - 1.0f;
    float u = f * 2.0f + (-0.99999994f);
    u = fmaxf(-0.99999994f, u);
    float w = -log1pf(-u * u);
    float p;
    if (w < 5.0f) {
        w -= 2.5f;
        p = 2.81022636e-08f;
        p = fmaf(p, w, 3.43273939e-07f);
        p = fmaf(p, w, -3.5233877e-06f);
        p = fmaf(p, w, -4.39150654e-06f);
        p = fmaf(p, w, 0.00021858087f);
        p = fmaf(p, w, -0.00125372503f);
        p = fmaf(p, w, -0.00417768164f);
        p = fmaf(p, w, 0.246640727f);
        p = fmaf(p, w, 1.50140941f);
    } else {
        w = sqrtf(w) - 3.0f;
        p = -0.000200214257f;
        p = fmaf(p, w, 0.000100950558f);
        p = fmaf(p, w, 0.00134934322f);
        p = fmaf(p, w, -0.00367342844f);
        p = fmaf(p, w, 0.00573950773f);
        p = fmaf(p, w, -0.0076224613f);
        p = fmaf(p, w, 0.00943887047f);
        p = fmaf(p, w, 1.00167406f);
        p = fmaf(p, w, 2.83297682f);
    }
    return 1.41421356f * (p * u);
}

// ---- XLA f32 tanh ----
__device__ __forceinline__ float xla_tanh(float x) {
    float ax = fabsf(x);
    float xc = fminf(fmaxf(x, -7.90531110763549805f), 7.90531110763549805f);
    float x2 = xc * xc;
    float np_ = -2.76076847742355e-16f;
    np_ = fmaf(np_, x2, 2.00018790482477e-13f);
    np_ = fmaf(np_, x2, -8.60467152213735e-11f);
    np_ = fmaf(np_, x2, 5.12229709037114e-08f);
    np_ = fmaf(np_, x2, 1.48572235717979e-05f);
    np_ = fmaf(np_, x2, 6.37261928875436e-04f);
    np_ = fmaf(np_, x2, 4.89352455891786e-03f);
    float num = xc * np_;
    float dp_ = 1.19825839466702e-06f;
    dp_ = fmaf(dp_, x2, 1.18534705686654e-04f);
    dp_ = fmaf(dp_, x2, 2.26843463243900e-03f);
    dp_ = fmaf(dp_, x2, 4.89352518554385e-03f);
    float r = num / dp_;
    return (ax < 0.0004f) ? x : r;
}

// ---- Fourier features into LDS buf[ i*TILE + lane ], rows 0..129 ----
// wave must be an SGPR value (readfirstlane'd) so fB loads are scalar.
__device__ __forceinline__ void compute_feats(const float* __restrict__ inp,
                                              const float* __restrict__ fB,
                                              float* buf, int lane, int wave, int base) {
    if (wave == 0) {
        float2 xy = reinterpret_cast<const float2*>(inp)[base + lane];
        buf[0 * TILE + lane] = xy.x;
        buf[1 * TILE + lane] = xy.y;
    }
    __syncthreads();
    float x0 = buf[0 * TILE + lane];
    float x1 = buf[1 * TILE + lane];
#pragma unroll 1
    for (int q = 0; q < 16; ++q) {
        int j = wave * 16 + q;                       // wave-uniform
        float dot = x0 * fB[j] + x1 * fB[64 + j];
        float pr = 6.2831855f * dot;
        buf[(2 + j) * TILE + lane]  = sinf(pr);
        buf[(66 + j) * TILE + lane] = cosf(pr);
    }
    __syncthreads();
}

// ---- layer-0: 16 outputs (o0..o0+15), float2 weight loads (rows 8B-aligned) ----
__device__ __forceinline__ void layer0_16(const float* __restrict__ W0,
                                          const float* __restrict__ b0,
                                          const float* fb, int lane, int o0,
                                          float acc[16]) {
#pragma unroll
    for (int k = 0; k < 16; ++k) acc[k] = b0[o0 + k];
#pragma unroll 1
    for (int i2 = 0; i2 < 65; ++i2) {
        float2 w[16];
#pragma unroll
        for (int k = 0; k < 16; ++k)
            w[k] = *reinterpret_cast<const float2*>(W0 + (o0 + k) * 130 + i2 * 2);
        float h0 = fb[(i2 * 2 + 0) * TILE + lane];
        float h1 = fb[(i2 * 2 + 1) * TILE + lane];
#pragma unroll
        for (int k = 0; k < 16; ++k) acc[k] = fmaf(h0, w[k].x, acc[k]);
#pragma unroll
        for (int k = 0; k < 16; ++k) acc[k] = fmaf(h1, w[k].y, acc[k]);
    }
}

// ---- generic 128->128 layer with tanh; 2 sections x 16 outputs per wave ----
__device__ __forceinline__ void mid_layer(const float* __restrict__ W,
                                          const float* __restrict__ b,
                                          const float* bin, float* bout,
                                          int lane, int wave) {
#pragma unroll 1
    for (int s = 0; s < 2; ++s) {
        int o0 = s * 64 + wave * 16;                 // wave-uniform
        float acc[16];
#pragma unroll
        for (int k = 0; k < 16; ++k) acc[k] = b[o0 + k];
#pragma unroll 1
        for (int i4 = 0; i4 < 32; ++i4) {
            float4 w[16];
#pragma unroll
            for (int k = 0; k < 16; ++k)
                w[k] = *reinterpret_cast<const float4*>(W + (o0 + k) * 128 + i4 * 4);
#pragma unroll
            for (int j = 0; j < 4; ++j) {
                float hv = bin[(i4 * 4 + j) * TILE + lane];
#pragma unroll
                for (int k = 0; k < 16; ++k) {
                    float wv = (j == 0) ? w[k].x : (j == 1) ? w[k].y : (j == 2) ? w[k].z : w[k].w;
                    acc[k] = fmaf(hv, wv, acc[k]);
                }
            }
        }
#pragma unroll
        for (int k = 0; k < 16; ++k)
            bout[(o0 + k) * TILE + lane] = xla_tanh(acc[k]);
    }
}

// ================= pass A: sum of y^2 over all N*128 layer-0 outputs ========
__global__ __launch_bounds__(256) void pass_a(const float* __restrict__ inp,
                                              const float* __restrict__ fB,
                                              const float* __restrict__ W0,
                                              const float* __restrict__ b0,
                                              double* __restrict__ ssq) {
    __shared__ float fb[130 * TILE];
    __shared__ double red[256];
    int t = threadIdx.x;
    int lane = t & 63;
    int wave = __builtin_amdgcn_readfirstlane(t >> 6);
    int base = blockIdx.x * TILE;

    compute_feats(inp, fB, fb, lane, wave, base);

    float ss = 0.f;
#pragma unroll 1
    for (int s = 0; s < 2; ++s) {
        int o0 = s * 64 + wave * 16;
        float acc[16];
        layer0_16(W0, b0, fb, lane, o0, acc);
#pragma unroll
        for (int k = 0; k < 16; ++k) ss = fmaf(acc[k], acc[k], ss);
    }
    red[t] = (double)ss;
    __syncthreads();
    for (int off = 128; off > 0; off >>= 1) {
        if (t < off) red[t] += red[t + off];
        __syncthreads();
    }
    if (t == 0) atomicAdd(&ssq[blockIdx.x & (NSLOTS - 1)], red[0]);
}

// ================= std finalize ============================================
__global__ void finalize_std(const double* __restrict__ ssq, float* __restrict__ stdp) {
    double s = 0.0;
    for (int i = 0; i < NSLOTS; ++i) s += ssq[i];
    float power = (float)(s / 128000000.0);
    float v = 0.f;
    if (isfinite(power) && power > 1.1920929e-07f) v = sqrtf(power / 1000.0f);
    *stdp = v;
}

// ================= pass B: full fused forward ==============================
__global__ __launch_bounds__(256) void pass_b(const float* __restrict__ inp,
                                              const float* __restrict__ fB,
                                              const float* __restrict__ W0, const float* __restrict__ b0,
                                              const float* __restrict__ W1, const float* __restrict__ b1,
                                              const float* __restrict__ W2, const float* __restrict__ b2,
                                              const float* __restrict__ W3, const float* __restrict__ b3,
                                              const float* __restrict__ W4, const float* __restrict__ b4,
                                              const float* __restrict__ stdp,
                                              float* __restrict__ out) {
    __shared__ float bufA[130 * TILE];
    __shared__ float bufB[128 * TILE];
    int t = threadIdx.x;
    int lane = t & 63;
    int wave = __builtin_amdgcn_readfirstlane(t >> 6);
    int base = blockIdx.x * TILE;

    compute_feats(inp, fB, bufA, lane, wave, base);
    float stdv = *stdp;

    // layer 0: bufA(130) -> bufB(128), STE noise + tanh
    unsigned n = (unsigned)(base + lane);
#pragma unroll 1
    for (int s = 0; s < 2; ++s) {
        int o0 = s * 64 + wave * 16;
        float acc[16];
        layer0_16(W0, b0, bufA, lane, o0, acc);
#pragma unroll
        for (int k = 0; k < 16; ++k) {
            float y   = acc[k];
            float nz  = jax_normal_f(n * 128u + (unsigned)(o0 + k));
            float yhw = y + nz * stdv;
            float h   = (yhw + y) - y;          // forward value of the STE expr
            bufB[(o0 + k) * TILE + lane] = xla_tanh(h);
        }
    }
    __syncthreads();

    mid_layer(W1, b1, bufB, bufA, lane, wave);
    __syncthreads();
    mid_layer(W2, b2, bufA, bufB, lane, wave);
    __syncthreads();
    mid_layer(W3, b3, bufB, bufA, lane, wave);
    __syncthreads();

    // layer 4: 128 -> 2, all 4 waves do 32-feature partials into bufB
    {
        float a0 = 0.f, a1 = 0.f;
#pragma unroll 1
        for (int i = 0; i < 32; ++i) {
            int f = wave * 32 + i;                   // wave-uniform W4 index
            float hv = bufA[f * TILE + lane];
            a0 = fmaf(hv, W4[f], a0);
            a1 = fmaf(hv, W4[128 + f], a1);
        }
        bufB[(wave * 2 + 0) * TILE + lane] = a0;
        bufB[(wave * 2 + 1) * TILE + lane] = a1;
    }
    __syncthreads();
    if (wave == 0) {
        float r0 = b4[0], r1 = b4[1];
#pragma unroll
        for (int w = 0; w < 4; ++w) {
            r0 += bufB[(w * 2 + 0) * TILE + lane];
            r1 += bufB[(w * 2 + 1) * TILE + lane];
        }
        reinterpret_cast<float2*>(out)[base + lane] = make_float2(r0, r1);
    }
}

extern "C" void kernel_launch(void* const* d_in, const int* in_sizes, int n_in,
                              void* d_out, int out_size, void* d_ws, size_t ws_size,
                              hipStream_t stream) {
    const float* inp = (const float*)d_in[0];
    const float* fB  = (const float*)d_in[1];
    const float* W0  = (const float*)d_in[2];
    const float* b0  = (const float*)d_in[3];
    const float* W1  = (const float*)d_in[4];
    const float* b1  = (const float*)d_in[5];
    const float* W2  = (const float*)d_in[6];
    const float* b2  = (const float*)d_in[7];
    const float* W3  = (const float*)d_in[8];
    const float* b3  = (const float*)d_in[9];
    const float* W4  = (const float*)d_in[10];
    const float* b4  = (const float*)d_in[11];
    float*  out  = (float*)d_out;
    double* ssq  = (double*)d_ws;                        // NSLOTS doubles
    float*  stdp = (float*)((char*)d_ws + NSLOTS * 8);   // then 1 float

    hipMemsetAsync(d_ws, 0, NSLOTS * 8, stream);
    pass_a<<<NBLK, 256, 0, stream>>>(inp, fB, W0, b0, ssq);
    finalize_std<<<1, 1, 0, stream>>>(ssq, stdp);
    pass_b<<<NBLK, 256, 0, stream>>>(inp, fB, W0, b0, W1, b1, W2, b2, W3, b3,
                                     W4, b4, stdp, out);
}

// Round 4
// 4668.393 us; speedup vs baseline: 9.6776x; 1.6162x over previous
//
#include <hip/hip_runtime.h>
#include <math.h>

#define NPTS   1000000
#define TILE   64
#define BLOCK  512               // 8 waves; wave w owns outputs w*16..w*16+15
#define NBLK   (NPTS / TILE)     // 15625
#define NSLOTS 256               // f64 partial-sum slots in ws

__device__ __forceinline__ unsigned rotl32(unsigned v, int r) {
    return (v << r) | (v >> (32 - r));
}

// ---- JAX partitionable threefry2x32, key=(0,42) ----
// bits = x0_out ^ x1_out with cipher inputs (0, idx); uniform(-1+ulp,1); XLA ErfInv32.
__device__ __forceinline__ float jax_normal_f(unsigned idx) {
    const unsigned ks0 = 0u, ks1 = 42u, ks2 = (0u ^ 42u ^ 0x1BD11BDAu);
    unsigned x0 = 0u + ks0;
    unsigned x1 = idx + ks1;
#define TFR(r) { x0 += x1; x1 = rotl32(x1, (r)); x1 ^= x0; }
    TFR(13) TFR(15) TFR(26) TFR(6)  x0 += ks1; x1 += ks2 + 1u;
    TFR(17) TFR(29) TFR(16) TFR(24) x0 += ks2; x1 += ks0 + 2u;
    TFR(13) TFR(15) TFR(26) TFR(6)  x0 += ks0; x1 += ks1 + 3u;
    TFR(17) TFR(29) TFR(16) TFR(24) x0 += ks1; x1 += ks2 + 4u;
    TFR(13) TFR(15) TFR(26) TFR(6)  x0 += ks2; x1 += ks0 + 5u;
#undef TFR
    unsigned bits = x0 ^ x1;
    float f = __uint_as_float((bits >> 9) | 0x3f800000u) - 1.0f;
    float u = f * 2.0f + (-0.99999994f);
    u = fmaxf(-0.99999994f, u);
    float w = -log1pf(-u * u);
    float p;
    if (w < 5.0f) {
        w -= 2.5f;
        p = 2.81022636e-08f;
        p = fmaf(p, w, 3.43273939e-07f);
        p = fmaf(p, w, -3.5233877e-06f);
        p = fmaf(p, w, -4.39150654e-06f);
        p = fmaf(p, w, 0.00021858087f);
        p = fmaf(p, w, -0.00125372503f);
        p = fmaf(p, w, -0.00417768164f);
        p = fmaf(p, w, 0.246640727f);
        p = fmaf(p, w, 1.50140941f);
    } else {
        w = sqrtf(w) - 3.0f;
        p = -0.000200214257f;
        p = fmaf(p, w, 0.000100950558f);
        p = fmaf(p, w, 0.00134934322f);
        p = fmaf(p, w, -0.00367342844f);
        p = fmaf(p, w, 0.00573950773f);
        p = fmaf(p, w, -0.0076224613f);
        p = fmaf(p, w, 0.00943887047f);
        p = fmaf(p, w, 1.00167406f);
        p = fmaf(p, w, 2.83297682f);
    }
    return 1.41421356f * (p * u);
}

// ---- XLA f32 tanh ----
__device__ __forceinline__ float xla_tanh(float x) {
    float ax = fabsf(x);
    float xc = fminf(fmaxf(x, -7.90531110763549805f), 7.90531110763549805f);
    float x2 = xc * xc;
    float np_ = -2.76076847742355e-16f;
    np_ = fmaf(np_, x2, 2.00018790482477e-13f);
    np_ = fmaf(np_, x2, -8.60467152213735e-11f);
    np_ = fmaf(np_, x2, 5.12229709037114e-08f);
    np_ = fmaf(np_, x2, 1.48572235717979e-05f);
    np_ = fmaf(np_, x2, 6.37261928875436e-04f);
    np_ = fmaf(np_, x2, 4.89352455891786e-03f);
    float num = xc * np_;
    float dp_ = 1.19825839466702e-06f;
    dp_ = fmaf(dp_, x2, 1.18534705686654e-04f);
    dp_ = fmaf(dp_, x2, 2.26843463243900e-03f);
    dp_ = fmaf(dp_, x2, 4.89352518554385e-03f);
    float r = num / dp_;
    return (ax < 0.0004f) ? x : r;
}

// ---- Fourier features into LDS buf rows 0..129; 8 waves x 8 features ----
__device__ __forceinline__ void compute_feats(const float* __restrict__ inp,
                                              const float* __restrict__ fB,
                                              float* buf, int lane, int wave, int base) {
    if (wave == 0) {
        float2 xy = reinterpret_cast<const float2*>(inp)[base + lane];
        buf[0 * TILE + lane] = xy.x;
        buf[1 * TILE + lane] = xy.y;
    }
    __syncthreads();
    float x0 = buf[0 * TILE + lane];
    float x1 = buf[1 * TILE + lane];
#pragma unroll 1
    for (int q = 0; q < 8; ++q) {
        int j = wave * 8 + q;                        // wave-uniform
        float dot = x0 * fB[j] + x1 * fB[64 + j];
        float pr = 6.2831855f * dot;
        buf[(2 + j) * TILE + lane]  = sinf(pr);
        buf[(66 + j) * TILE + lane] = cosf(pr);
    }
    __syncthreads();
}

// ---- layer-0: 16 outputs (o0..o0+15), float2 weight loads (rows 8B-aligned) ----
__device__ __forceinline__ void layer0_16(const float* __restrict__ W0,
                                          const float* __restrict__ b0,
                                          const float* fb, int lane, int o0,
                                          float acc[16]) {
#pragma unroll
    for (int k = 0; k < 16; ++k) acc[k] = b0[o0 + k];
#pragma unroll 1
    for (int i2 = 0; i2 < 65; ++i2) {
        float2 w[16];
#pragma unroll
        for (int k = 0; k < 16; ++k)
            w[k] = *reinterpret_cast<const float2*>(W0 + (o0 + k) * 130 + i2 * 2);
        float h0 = fb[(i2 * 2 + 0) * TILE + lane];
        float h1 = fb[(i2 * 2 + 1) * TILE + lane];
#pragma unroll
        for (int k = 0; k < 16; ++k) acc[k] = fmaf(h0, w[k].x, acc[k]);
#pragma unroll
        for (int k = 0; k < 16; ++k) acc[k] = fmaf(h1, w[k].y, acc[k]);
    }
}

// ---- generic 128->128 layer with tanh; one 16-output section per wave ----
__device__ __forceinline__ void mid_layer(const float* __restrict__ W,
                                          const float* __restrict__ b,
                                          const float* bin, float* bout,
                                          int lane, int wave) {
    int o0 = wave * 16;                              // wave-uniform
    float acc[16];
#pragma unroll
    for (int k = 0; k < 16; ++k) acc[k] = b[o0 + k];
#pragma unroll 1
    for (int i4 = 0; i4 < 32; ++i4) {
        float4 w[16];
#pragma unroll
        for (int k = 0; k < 16; ++k)
            w[k] = *reinterpret_cast<const float4*>(W + (o0 + k) * 128 + i4 * 4);
#pragma unroll
        for (int j = 0; j < 4; ++j) {
            float hv = bin[(i4 * 4 + j) * TILE + lane];
#pragma unroll
            for (int k = 0; k < 16; ++k) {
                float wv = (j == 0) ? w[k].x : (j == 1) ? w[k].y : (j == 2) ? w[k].z : w[k].w;
                acc[k] = fmaf(hv, wv, acc[k]);
            }
        }
    }
#pragma unroll
    for (int k = 0; k < 16; ++k)
        bout[(o0 + k) * TILE + lane] = xla_tanh(acc[k]);
}

// ================= pass A: sum of y^2 over all N*128 layer-0 outputs ========
__global__ __launch_bounds__(BLOCK, 6) void pass_a(const float* __restrict__ inp,
                                                   const float* __restrict__ fB,
                                                   const float* __restrict__ W0,
                                                   const float* __restrict__ b0,
                                                   double* __restrict__ ssq) {
    __shared__ float fb[130 * TILE];
    __shared__ double red[8];
    int t = threadIdx.x;
    int lane = t & 63;
    int wave = __builtin_amdgcn_readfirstlane(t >> 6);
    int base = blockIdx.x * TILE;

    compute_feats(inp, fB, fb, lane, wave, base);

    float ss = 0.f;
    {
        int o0 = wave * 16;
        float acc[16];
        layer0_16(W0, b0, fb, lane, o0, acc);
#pragma unroll
        for (int k = 0; k < 16; ++k) ss = fmaf(acc[k], acc[k], ss);
    }
#pragma unroll
    for (int off = 32; off > 0; off >>= 1) ss += __shfl_down(ss, off, 64);
    if (lane == 0) red[wave] = (double)ss;
    __syncthreads();
    if (t == 0) {
        double s = 0.0;
#pragma unroll
        for (int w = 0; w < 8; ++w) s += red[w];
        atomicAdd(&ssq[blockIdx.x & (NSLOTS - 1)], s);
    }
}

// ================= std finalize ============================================
__global__ void finalize_std(const double* __restrict__ ssq, float* __restrict__ stdp) {
    double s = 0.0;
    for (int i = 0; i < NSLOTS; ++i) s += ssq[i];
    float power = (float)(s / 128000000.0);
    float v = 0.f;
    if (isfinite(power) && power > 1.1920929e-07f) v = sqrtf(power / 1000.0f);
    *stdp = v;
}

// ================= pass B: full fused forward ==============================
__global__ __launch_bounds__(BLOCK, 4) void pass_b(const float* __restrict__ inp,
                                              const float* __restrict__ fB,
                                              const float* __restrict__ W0, const float* __restrict__ b0,
                                              const float* __restrict__ W1, const float* __restrict__ b1,
                                              const float* __restrict__ W2, const float* __restrict__ b2,
                                              const float* __restrict__ W3, const float* __restrict__ b3,
                                              const float* __restrict__ W4, const float* __restrict__ b4,
                                              const float* __restrict__ stdp,
                                              float* __restrict__ out) {
    __shared__ float bufA[130 * TILE];
    __shared__ float bufB[128 * TILE];
    int t = threadIdx.x;
    int lane = t & 63;
    int wave = __builtin_amdgcn_readfirstlane(t >> 6);
    int base = blockIdx.x * TILE;

    compute_feats(inp, fB, bufA, lane, wave, base);
    float stdv = *stdp;

    // layer 0: bufA(130) -> bufB(128), STE noise + tanh
    unsigned n = (unsigned)(base + lane);
    {
        int o0 = wave * 16;
        float acc[16];
        layer0_16(W0, b0, bufA, lane, o0, acc);
#pragma unroll
        for (int k = 0; k < 16; ++k) {
            float y   = acc[k];
            float nz  = jax_normal_f(n * 128u + (unsigned)(o0 + k));
            float yhw = y + nz * stdv;
            float h   = (yhw + y) - y;          // forward value of the STE expr
            bufB[(o0 + k) * TILE + lane] = xla_tanh(h);
        }
    }
    __syncthreads();

    mid_layer(W1, b1, bufB, bufA, lane, wave);
    __syncthreads();
    mid_layer(W2, b2, bufA, bufB, lane, wave);
    __syncthreads();
    mid_layer(W3, b3, bufB, bufA, lane, wave);
    __syncthreads();

    // layer 4: 128 -> 2; 8 waves x 16-feature partials into bufB rows 0..15
    {
        float a0 = 0.f, a1 = 0.f;
#pragma unroll 1
        for (int i = 0; i < 16; ++i) {
            int f = wave * 16 + i;                   // wave-uniform W4 index
            float hv = bufA[f * TILE + lane];
            a0 = fmaf(hv, W4[f], a0);
            a1 = fmaf(hv, W4[128 + f], a1);
        }
        bufB[(wave * 2 + 0) * TILE + lane] = a0;
        bufB[(wave * 2 + 1) * TILE + lane] = a1;
    }
    __syncthreads();
    if (wave == 0) {
        float r0 = b4[0], r1 = b4[1];
#pragma unroll
        for (int w = 0; w < 8; ++w) {
            r0 += bufB[(w * 2 + 0) * TILE + lane];
            r1 += bufB[(w * 2 + 1) * TILE + lane];
        }
        reinterpret_cast<float2*>(out)[base + lane] = make_float2(r0, r1);
    }
}

extern "C" void kernel_launch(void* const* d_in, const int* in_sizes, int n_in,
                              void* d_out, int out_size, void* d_ws, size_t ws_size,
                              hipStream_t stream) {
    const float* inp = (const float*)d_in[0];
    const float* fB  = (const float*)d_in[1];
    const float* W0  = (const float*)d_in[2];
    const float* b0  = (const float*)d_in[3];
    const float* W1  = (const float*)d_in[4];
    const float* b1  = (const float*)d_in[5];
    const float* W2  = (const float*)d_in[6];
    const float* b2  = (const float*)d_in[7];
    const float* W3  = (const float*)d_in[8];
    const float* b3  = (const float*)d_in[9];
    const float* W4  = (const float*)d_in[10];
    const float* b4  = (const float*)d_in[11];
    float*  out  = (float*)d_out;
    double* ssq  = (double*)d_ws;                        // NSLOTS doubles
    float*  stdp = (float*)((char*)d_ws + NSLOTS * 8);   // then 1 float

    hipMemsetAsync(d_ws, 0, NSLOTS * 8, stream);
    pass_a<<<NBLK, BLOCK, 0, stream>>>(inp, fB, W0, b0, ssq);
    finalize_std<<<1, 1, 0, stream>>>(ssq, stdp);
    pass_b<<<NBLK, BLOCK, 0, stream>>>(inp, fB, W0, b0, W1, b1, W2, b2, W3, b3,
                                       W4, b4, stdp, out);
}

// Round 5
// 1245.475 us; speedup vs baseline: 36.2745x; 3.7483x over previous
//
#include <hip/hip_runtime.h>
#include <math.h>

#define NPTS   1000000
#define TILE   32                // points per block
#define BLOCK  512               // 8 waves; wave w owns output rows 16w..16w+15
#define NBLK   (NPTS / TILE)     // 31250
#define NSLOTS 256               // f64 partial-sum slots in ws
#define LROW   132               // padded LDS row stride (u32 words) per point
#define WS_WPACK_OFF 2064        // byte offset of weight-frag region in ws
#define HEADU  (4 * 2048 * 8)    // uint offset of layer0 head within wpack
// wpack layout (uint units): W0sc @0, W1 @16384, W2 @32768, W3 @49152, head @65536

typedef __attribute__((ext_vector_type(8))) short bf16x8;
typedef __attribute__((ext_vector_type(4))) float f32x4;

union U4B { uint4 u; bf16x8 v; };
__device__ __forceinline__ bf16x8 asfrag(uint4 u) { U4B x; x.u = u; return x.v; }
__device__ __forceinline__ bf16x8 frag4(uint a, uint b, uint c, uint d) {
    U4B x; x.u = make_uint4(a, b, c, d); return x.v;
}
__device__ __forceinline__ f32x4 mfma16(bf16x8 a, bf16x8 b, f32x4 c) {
    return __builtin_amdgcn_mfma_f32_16x16x32_bf16(a, b, c, 0, 0, 0);
}

__device__ __forceinline__ unsigned rotl32(unsigned v, int r) {
    return (v << r) | (v >> (32 - r));
}

// ---- JAX partitionable threefry2x32 key=(0,42); uniform(-1+ulp,1); ErfInv32 ----
__device__ __forceinline__ float jax_normal_f(unsigned idx) {
    const unsigned ks0 = 0u, ks1 = 42u, ks2 = (0u ^ 42u ^ 0x1BD11BDAu);
    unsigned x0 = 0u + ks0;
    unsigned x1 = idx + ks1;
#define TFR(r) { x0 += x1; x1 = rotl32(x1, (r)); x1 ^= x0; }
    TFR(13) TFR(15) TFR(26) TFR(6)  x0 += ks1; x1 += ks2 + 1u;
    TFR(17) TFR(29) TFR(16) TFR(24) x0 += ks2; x1 += ks0 + 2u;
    TFR(13) TFR(15) TFR(26) TFR(6)  x0 += ks0; x1 += ks1 + 3u;
    TFR(17) TFR(29) TFR(16) TFR(24) x0 += ks1; x1 += ks2 + 4u;
    TFR(13) TFR(15) TFR(26) TFR(6)  x0 += ks2; x1 += ks0 + 5u;
#undef TFR
    unsigned bits = x0 ^ x1;
    float f = __uint_as_float((bits >> 9) | 0x3f800000u) - 1.0f;
    float u = f * 2.0f + (-0.99999994f);
    u = fmaxf(-0.99999994f, u);
    float w = -__logf(fmaf(-u, u, 1.0f));    // -log(1-u^2), fma keeps precision
    float p;
    if (w < 5.0f) {
        w -= 2.5f;
        p = 2.81022636e-08f;
        p = fmaf(p, w, 3.43273939e-07f);
        p = fmaf(p, w, -3.5233877e-06f);
        p = fmaf(p, w, -4.39150654e-06f);
        p = fmaf(p, w, 0.00021858087f);
        p = fmaf(p, w, -0.00125372503f);
        p = fmaf(p, w, -0.00417768164f);
        p = fmaf(p, w, 0.246640727f);
        p = fmaf(p, w, 1.50140941f);
    } else {
        w = sqrtf(w) - 3.0f;
        p = -0.000200214257f;
        p = fmaf(p, w, 0.000100950558f);
        p = fmaf(p, w, 0.00134934322f);
        p = fmaf(p, w, -0.00367342844f);
        p = fmaf(p, w, 0.00573950773f);
        p = fmaf(p, w, -0.0076224613f);
        p = fmaf(p, w, 0.00943887047f);
        p = fmaf(p, w, 1.00167406f);
        p = fmaf(p, w, 2.83297682f);
    }
    return 1.41421356f * (p * u);
}

// ---- XLA-style f32 tanh (rcp instead of div: ~1ulp, huge slack available) ----
__device__ __forceinline__ float xla_tanh(float x) {
    float ax = fabsf(x);
    float xc = fminf(fmaxf(x, -7.90531110763549805f), 7.90531110763549805f);
    float x2 = xc * xc;
    float np_ = -2.76076847742355e-16f;
    np_ = fmaf(np_, x2, 2.00018790482477e-13f);
    np_ = fmaf(np_, x2, -8.60467152213735e-11f);
    np_ = fmaf(np_, x2, 5.12229709037114e-08f);
    np_ = fmaf(np_, x2, 1.48572235717979e-05f);
    np_ = fmaf(np_, x2, 6.37261928875436e-04f);
    np_ = fmaf(np_, x2, 4.89352455891786e-03f);
    float num = xc * np_;
    float dp_ = 1.19825839466702e-06f;
    dp_ = fmaf(dp_, x2, 1.18534705686654e-04f);
    dp_ = fmaf(dp_, x2, 2.26843463243900e-03f);
    dp_ = fmaf(dp_, x2, 4.89352518554385e-03f);
    float r = num * __builtin_amdgcn_rcpf(dp_);
    return (ax < 0.0004f) ? x : r;
}

// ---- pack two floats into two (bf16hi<<16 | bf16lo) words via v_cvt_pk ----
__device__ __forceinline__ uint2 pack2_bf16split(float a, float b) {
    uint hp, lp;
    asm("v_cvt_pk_bf16_f32 %0, %1, %2" : "=v"(hp) : "v"(a), "v"(b));
    float ra = a - __uint_as_float(hp << 16);
    float rb = b - __uint_as_float(hp & 0xFFFF0000u);
    asm("v_cvt_pk_bf16_f32 %0, %1, %2" : "=v"(lp) : "v"(ra), "v"(rb));
    uint ua = (hp << 16) | (lp & 0xFFFFu);
    uint ub = (hp & 0xFFFF0000u) | (lp >> 16);
    return make_uint2(ua, ub);
}

__device__ __forceinline__ ushort bf16rne(float x) {
    unsigned b = __float_as_uint(x);
    b += 0x7FFFu + ((b >> 16) & 1u);
    return (ushort)(b >> 16);
}

// ---- Fourier features -> buf (point-major packed), k=j:sin, k=64+j:cos ----
__device__ __forceinline__ void feats_stage(const float2* __restrict__ inp2,
                                            const float* __restrict__ fB,
                                            uint* buf, int t, int base) {
    int p = t & 31, jg = t >> 5;            // 16 j-groups x 4 features
    float2 xy = inp2[base + p];
#pragma unroll 1
    for (int q = 0; q < 4; ++q) {
        int j = jg * 4 + q;
        float dot = xy.x * fB[j] + xy.y * fB[64 + j];
        float pr = 6.2831855f * dot;
        float s = sinf(pr), c = cosf(pr);
        uint2 pk = pack2_bf16split(s, c);
        buf[p * LROW + j] = pk.x;
        buf[p * LROW + 64 + j] = pk.y;
    }
    __syncthreads();
}

// ---- 16x32-tiled GEMM core: acc[pt][r] = sum_k W[row][k] * h[k][point] ----
// rows = 16*wave + (lane>>4)*4 + r ; points = pt*16 + (lane&15); K = 128
__device__ __forceinline__ void gemm16x32(const uint* __restrict__ wp,
                                          const uint* buf, int lane, int wave,
                                          f32x4 acc[2]) {
    f32x4 z = {0.f, 0.f, 0.f, 0.f};
    acc[0] = z; acc[1] = z;
    int lq = lane >> 4, lr = lane & 15;
#pragma unroll 1
    for (int kt = 0; kt < 4; ++kt) {
        const uint4* wf = (const uint4*)wp + ((wave * 4 + kt) * 64 + lane) * 2;
        bf16x8 Ahi = asfrag(wf[0]);
        bf16x8 Alo = asfrag(wf[1]);
#pragma unroll
        for (int pt = 0; pt < 2; ++pt) {
            const uint4* bw = (const uint4*)(buf + (pt * 16 + lr) * LROW + kt * 32 + lq * 8);
            uint4 b0v = bw[0], b1v = bw[1];
            bf16x8 Bhi = frag4((b0v.x >> 16) | (b0v.y & 0xFFFF0000u),
                               (b0v.z >> 16) | (b0v.w & 0xFFFF0000u),
                               (b1v.x >> 16) | (b1v.y & 0xFFFF0000u),
                               (b1v.z >> 16) | (b1v.w & 0xFFFF0000u));
            bf16x8 Blo = frag4((b0v.x & 0xFFFFu) | (b0v.y << 16),
                               (b0v.z & 0xFFFFu) | (b0v.w << 16),
                               (b1v.x & 0xFFFFu) | (b1v.y << 16),
                               (b1v.z & 0xFFFFu) | (b1v.w << 16));
            acc[pt] = mfma16(Ahi, Blo, acc[pt]);
            acc[pt] = mfma16(Alo, Bhi, acc[pt]);
            acc[pt] = mfma16(Ahi, Bhi, acc[pt]);
        }
    }
}

// ---- layer0 raw y values (MFMA over sin/cos + explicit b0 + W[:,0:2]*x) ----
__device__ __forceinline__ void layer0_vals(const uint* __restrict__ wpack,
                                            const float2* __restrict__ inp2, int base,
                                            const uint* bin, int lane, int wave,
                                            float y[2][4]) {
    f32x4 acc[2];
    gemm16x32(wpack, bin, lane, wave, acc);
    int lq = lane >> 4, lr = lane & 15;
    const float4* head = (const float4*)(wpack + HEADU);
    float4 hd[4];
#pragma unroll
    for (int r = 0; r < 4; ++r) hd[r] = head[wave * 16 + lq * 4 + r];
#pragma unroll
    for (int pt = 0; pt < 2; ++pt) {
        float2 xy = inp2[base + pt * 16 + lr];
#pragma unroll
        for (int r = 0; r < 4; ++r)
            y[pt][r] = acc[pt][r] + (hd[r].x + hd[r].y * xy.x + hd[r].z * xy.y);
    }
}

// ---- mid layer: y = tanh(W h + b), packed write ----
__device__ __forceinline__ void mid_layer(const uint* __restrict__ wp,
                                          const float* __restrict__ bias,
                                          const uint* bin, uint* bout,
                                          int lane, int wave) {
    f32x4 acc[2];
    gemm16x32(wp, bin, lane, wave, acc);
    int lq = lane >> 4, lr = lane & 15;
    float4 bv = *(const float4*)&bias[wave * 16 + lq * 4];
#pragma unroll
    for (int pt = 0; pt < 2; ++pt) {
        float t0 = xla_tanh(acc[pt][0] + bv.x);
        float t1 = xla_tanh(acc[pt][1] + bv.y);
        float t2 = xla_tanh(acc[pt][2] + bv.z);
        float t3 = xla_tanh(acc[pt][3] + bv.w);
        uint2 p01 = pack2_bf16split(t0, t1);
        uint2 p23 = pack2_bf16split(t2, t3);
        *(uint4*)&bout[(pt * 16 + lr) * LROW + wave * 16 + lq * 4] =
            make_uint4(p01.x, p01.y, p23.x, p23.y);
    }
}

// ================= prepack: split weights into frag-ready bf16 hi/lo ========
__global__ void prepack(const float* __restrict__ W0, const float* __restrict__ b0,
                        const float* __restrict__ W1, const float* __restrict__ W2,
                        const float* __restrict__ W3, uint* __restrict__ wpack) {
    int tid = blockIdx.x * 256 + threadIdx.x;
    if (tid < 8192) {
        int mat = tid >> 11, slot = tid & 2047;
        int m = slot >> 8, kt = (slot >> 6) & 3, l = slot & 63;
        int row = m * 16 + (l & 15), kb = kt * 32 + ((l >> 4) << 3);
        const float* W; int stride, coff;
        if (mat == 0)      { W = W0; stride = 130; coff = 2; }
        else if (mat == 1) { W = W1; stride = 128; coff = 0; }
        else if (mat == 2) { W = W2; stride = 128; coff = 0; }
        else               { W = W3; stride = 128; coff = 0; }
        uint hi[8], lo[8];
#pragma unroll
        for (int i = 0; i < 8; ++i) {
            float w = W[row * stride + coff + kb + i];
            ushort h = bf16rne(w);
            float hf = __uint_as_float((uint)h << 16);
            hi[i] = h; lo[i] = bf16rne(w - hf);
        }
        uint* dst = wpack + (uint)tid * 8;
        dst[0] = hi[0] | (hi[1] << 16); dst[1] = hi[2] | (hi[3] << 16);
        dst[2] = hi[4] | (hi[5] << 16); dst[3] = hi[6] | (hi[7] << 16);
        dst[4] = lo[0] | (lo[1] << 16); dst[5] = lo[2] | (lo[3] << 16);
        dst[6] = lo[4] | (lo[5] << 16); dst[7] = lo[6] | (lo[7] << 16);
    } else if (tid < 8320) {
        int row = tid - 8192;
        float4 h;
        h.x = b0[row]; h.y = W0[row * 130]; h.z = W0[row * 130 + 1]; h.w = 0.f;
        ((float4*)(wpack + HEADU))[row] = h;
    }
}

// ================= pass A: sum y^2 over all N*128 layer-0 outputs ===========
__global__ __launch_bounds__(BLOCK, 8) void pass_a(const float2* __restrict__ inp2,
                                                   const float* __restrict__ fB,
                                                   const uint* __restrict__ wpack,
                                                   double* __restrict__ ssq) {
    __shared__ __align__(16) uint buf0[TILE * LROW];
    __shared__ double red[8];
    int t = threadIdx.x;
    int lane = t & 63;
    int wave = __builtin_amdgcn_readfirstlane(t >> 6);
    int base = blockIdx.x * TILE;

    feats_stage(inp2, fB, buf0, t, base);
    float y[2][4];
    layer0_vals(wpack, inp2, base, buf0, lane, wave, y);

    float ss = 0.f;
#pragma unroll
    for (int pt = 0; pt < 2; ++pt)
#pragma unroll
        for (int r = 0; r < 4; ++r) ss = fmaf(y[pt][r], y[pt][r], ss);
#pragma unroll
    for (int off = 32; off > 0; off >>= 1) ss += __shfl_down(ss, off, 64);
    if (lane == 0) red[wave] = (double)ss;
    __syncthreads();
    if (t == 0) {
        double s = 0.0;
#pragma unroll
        for (int w = 0; w < 8; ++w) s += red[w];
        atomicAdd(&ssq[blockIdx.x & (NSLOTS - 1)], s);
    }
}

// ================= std finalize ============================================
__global__ void finalize_std(const double* __restrict__ ssq, float* __restrict__ stdp) {
    double s = 0.0;
    for (int i = 0; i < NSLOTS; ++i) s += ssq[i];
    float power = (float)(s / 128000000.0);
    float v = 0.f;
    if (isfinite(power) && power > 1.1920929e-07f) v = sqrtf(power / 1000.0f);
    *stdp = v;
}

// ================= pass B: full fused forward ==============================
__global__ __launch_bounds__(BLOCK, 8) void pass_b(const float2* __restrict__ inp2,
                                                   const float* __restrict__ fB,
                                                   const uint* __restrict__ wpack,
                                                   const float* __restrict__ b1,
                                                   const float* __restrict__ b2,
                                                   const float* __restrict__ b3,
                                                   const float* __restrict__ W4,
                                                   const float* __restrict__ b4,
                                                   const float* __restrict__ stdp,
                                                   float* __restrict__ out) {
    __shared__ __align__(16) uint buf0[TILE * LROW];
    __shared__ __align__(16) uint buf1[TILE * LROW];
    __shared__ float pa[16][TILE][2];
    int t = threadIdx.x;
    int lane = t & 63;
    int wave = __builtin_amdgcn_readfirstlane(t >> 6);
    int base = blockIdx.x * TILE;

    feats_stage(inp2, fB, buf0, t, base);
    float stdv = *stdp;

    // layer 0: MFMA + STE noise + tanh -> buf1
    {
        float y[2][4];
        layer0_vals(wpack, inp2, base, buf0, lane, wave, y);
        int lq = lane >> 4, lr = lane & 15;
#pragma unroll
        for (int pt = 0; pt < 2; ++pt) {
            unsigned pidx = (unsigned)(base + pt * 16 + lr);
            float tv[4];
#pragma unroll
            for (int r = 0; r < 4; ++r) {
                float yy = y[pt][r];
                unsigned row = (unsigned)(wave * 16 + lq * 4 + r);
                float nz = jax_normal_f(pidx * 128u + row);
                float yhw = yy + nz * stdv;
                float h = (yhw + yy) - yy;      // forward value of the STE expr
                tv[r] = xla_tanh(h);
            }
            uint2 p01 = pack2_bf16split(tv[0], tv[1]);
            uint2 p23 = pack2_bf16split(tv[2], tv[3]);
            *(uint4*)&buf1[(pt * 16 + lr) * LROW + wave * 16 + lq * 4] =
                make_uint4(p01.x, p01.y, p23.x, p23.y);
        }
    }
    __syncthreads();

    mid_layer(wpack + 16384, b1, buf1, buf0, lane, wave);
    __syncthreads();
    mid_layer(wpack + 32768, b2, buf0, buf1, lane, wave);
    __syncthreads();
    mid_layer(wpack + 49152, b3, buf1, buf0, lane, wave);
    __syncthreads();

    // layer 4: 128 -> 2 ; 16 f-groups x 32 points
    {
        int p = t & 31, g = t >> 5;
        const uint4* hp = (const uint4*)&buf0[p * LROW + g * 8];
        uint4 h0 = hp[0], h1 = hp[1];
        float4 wA = *(const float4*)&W4[g * 8];
        float4 wB = *(const float4*)&W4[g * 8 + 4];
        float4 wC = *(const float4*)&W4[128 + g * 8];
        float4 wD = *(const float4*)&W4[128 + g * 8 + 4];
        float hv[8];
        hv[0] = __uint_as_float(h0.x & 0xFFFF0000u) + __uint_as_float(h0.x << 16);
        hv[1] = __uint_as_float(h0.y & 0xFFFF0000u) + __uint_as_float(h0.y << 16);
        hv[2] = __uint_as_float(h0.z & 0xFFFF0000u) + __uint_as_float(h0.z << 16);
        hv[3] = __uint_as_float(h0.w & 0xFFFF0000u) + __uint_as_float(h0.w << 16);
        hv[4] = __uint_as_float(h1.x & 0xFFFF0000u) + __uint_as_float(h1.x << 16);
        hv[5] = __uint_as_float(h1.y & 0xFFFF0000u) + __uint_as_float(h1.y << 16);
        hv[6] = __uint_as_float(h1.z & 0xFFFF0000u) + __uint_as_float(h1.z << 16);
        hv[7] = __uint_as_float(h1.w & 0xFFFF0000u) + __uint_as_float(h1.w << 16);
        float a0 = 0.f, a1 = 0.f;
        a0 = fmaf(hv[0], wA.x, a0); a0 = fmaf(hv[1], wA.y, a0);
        a0 = fmaf(hv[2], wA.z, a0); a0 = fmaf(hv[3], wA.w, a0);
        a0 = fmaf(hv[4], wB.x, a0); a0 = fmaf(hv[5], wB.y, a0);
        a0 = fmaf(hv[6], wB.z, a0); a0 = fmaf(hv[7], wB.w, a0);
        a1 = fmaf(hv[0], wC.x, a1); a1 = fmaf(hv[1], wC.y, a1);
        a1 = fmaf(hv[2], wC.z, a1); a1 = fmaf(hv[3], wC.w, a1);
        a1 = fmaf(hv[4], wD.x, a1); a1 = fmaf(hv[5], wD.y, a1);
        a1 = fmaf(hv[6], wD.z, a1); a1 = fmaf(hv[7], wD.w, a1);
        pa[g][p][0] = a0; pa[g][p][1] = a1;
    }
    __syncthreads();
    if (t < 64) {
        int p = t & 31, j = t >> 5;
        float r = b4[j];
#pragma unroll
        for (int g = 0; g < 16; ++g) r += pa[g][p][j];
        out[(base + p) * 2 + j] = r;
    }
}

extern "C" void kernel_launch(void* const* d_in, const int* in_sizes, int n_in,
                              void* d_out, int out_size, void* d_ws, size_t ws_size,
                              hipStream_t stream) {
    const float* inp = (const float*)d_in[0];
    const float* fB  = (const float*)d_in[1];
    const float* W0  = (const float*)d_in[2];
    const float* b0  = (const float*)d_in[3];
    const float* W1  = (const float*)d_in[4];
    const float* b1  = (const float*)d_in[5];
    const float* W2  = (const float*)d_in[6];
    const float* b2  = (const float*)d_in[7];
    const float* W3  = (const float*)d_in[8];
    const float* b3  = (const float*)d_in[9];
    const float* W4  = (const float*)d_in[10];
    const float* b4  = (const float*)d_in[11];
    float*  out  = (float*)d_out;
    double* ssq  = (double*)d_ws;                        // NSLOTS doubles
    float*  stdp = (float*)((char*)d_ws + NSLOTS * 8);   // then 1 float
    uint*   wpack = (uint*)((char*)d_ws + WS_WPACK_OFF); // frag-packed weights (~264KB)

    hipMemsetAsync(d_ws, 0, NSLOTS * 8, stream);
    prepack<<<33, 256, 0, stream>>>(W0, b0, W1, W2, W3, wpack);
    pass_a<<<NBLK, BLOCK, 0, stream>>>((const float2*)inp, fB, wpack, ssq);
    finalize_std<<<1, 1, 0, stream>>>(ssq, stdp);
    pass_b<<<NBLK, BLOCK, 0, stream>>>((const float2*)inp, fB, wpack,
                                       b1, b2, b3, W4, b4, stdp, out);
}

// Round 6
// 926.040 us; speedup vs baseline: 48.7873x; 1.3449x over previous
//
#include <hip/hip_runtime.h>
#include <math.h>

#define NPTS   1000000
#define TILE   32                // points per block
#define BLOCK  512               // 8 waves; wave w owns output rows 16w..16w+15
#define NBLK   (NPTS / TILE)     // 31250
#define NSLOTS 256               // f32 partial-sum slots in ws
#define LROW   132               // uints per point row: hi[0:64) lo[64:128) pad
#define WS_WPACK_OFF 2064        // byte offset of weight-frag region in ws
#define HEADU  (4 * 2048 * 8)    // uint offset of layer0 head within wpack

typedef __attribute__((ext_vector_type(8))) short bf16x8;
typedef __attribute__((ext_vector_type(4))) float f32x4;

union U4B { uint4 u; bf16x8 v; };
__device__ __forceinline__ bf16x8 asfrag(uint4 u) { U4B x; x.u = u; return x.v; }
__device__ __forceinline__ f32x4 mfma16(bf16x8 a, bf16x8 b, f32x4 c) {
    return __builtin_amdgcn_mfma_f32_16x16x32_bf16(a, b, c, 0, 0, 0);
}

__device__ __forceinline__ unsigned rotl32(unsigned v, int r) {
    return (v << r) | (v >> (32 - r));
}

// ---- JAX partitionable threefry2x32 key=(0,42); uniform(-1+ulp,1); ErfInv32 ----
__device__ __forceinline__ float jax_normal_f(unsigned idx) {
    const unsigned ks0 = 0u, ks1 = 42u, ks2 = (0u ^ 42u ^ 0x1BD11BDAu);
    unsigned x0 = 0u + ks0;
    unsigned x1 = idx + ks1;
#define TFR(r) { x0 += x1; x1 = rotl32(x1, (r)); x1 ^= x0; }
    TFR(13) TFR(15) TFR(26) TFR(6)  x0 += ks1; x1 += ks2 + 1u;
    TFR(17) TFR(29) TFR(16) TFR(24) x0 += ks2; x1 += ks0 + 2u;
    TFR(13) TFR(15) TFR(26) TFR(6)  x0 += ks0; x1 += ks1 + 3u;
    TFR(17) TFR(29) TFR(16) TFR(24) x0 += ks1; x1 += ks2 + 4u;
    TFR(13) TFR(15) TFR(26) TFR(6)  x0 += ks2; x1 += ks0 + 5u;
#undef TFR
    unsigned bits = x0 ^ x1;
    float f = __uint_as_float((bits >> 9) | 0x3f800000u) - 1.0f;
    float u = f * 2.0f + (-0.99999994f);
    u = fmaxf(-0.99999994f, u);
    float w = -__logf(fmaf(-u, u, 1.0f));
    float p;
    if (w < 5.0f) {
        w -= 2.5f;
        p = 2.81022636e-08f;
        p = fmaf(p, w, 3.43273939e-07f);
        p = fmaf(p, w, -3.5233877e-06f);
        p = fmaf(p, w, -4.39150654e-06f);
        p = fmaf(p, w, 0.00021858087f);
        p = fmaf(p, w, -0.00125372503f);
        p = fmaf(p, w, -0.00417768164f);
        p = fmaf(p, w, 0.246640727f);
        p = fmaf(p, w, 1.50140941f);
    } else {
        w = sqrtf(w) - 3.0f;
        p = -0.000200214257f;
        p = fmaf(p, w, 0.000100950558f);
        p = fmaf(p, w, 0.00134934322f);
        p = fmaf(p, w, -0.00367342844f);
        p = fmaf(p, w, 0.00573950773f);
        p = fmaf(p, w, -0.0076224613f);
        p = fmaf(p, w, 0.00943887047f);
        p = fmaf(p, w, 1.00167406f);
        p = fmaf(p, w, 2.83297682f);
    }
    return 1.41421356f * (p * u);
}

// ---- fast tanh: 1 - 2e/(1+e), e = exp(-2|x|), via v_exp_f32 ----
__device__ __forceinline__ float fast_tanh(float x) {
    float ax = fabsf(x);
    float e;
    asm("v_exp_f32 %0, %1" : "=v"(e) : "v"(ax * -2.88539008f)); // 2^(-2*log2e*ax)
    float r = __builtin_amdgcn_rcpf(1.0f + e);
    float t = fmaf(-2.0f * e, r, 1.0f);
    return copysignf(t, x);
}

// ---- sin/cos of 2*pi*d via hardware revolutions ----
__device__ __forceinline__ void sincos_rev(float d, float* s, float* c) {
    float fr;
    asm("v_fract_f32 %0, %1" : "=v"(fr) : "v"(d));
    asm("v_sin_f32 %0, %1" : "=v"(*s) : "v"(fr));
    asm("v_cos_f32 %0, %1" : "=v"(*c) : "v"(fr));
}

// ---- pack pair (a,b): .x = hi-plane word, .y = lo-plane word ----
__device__ __forceinline__ uint2 packpair(float a, float b) {
    uint hp, lp;
    asm("v_cvt_pk_bf16_f32 %0, %1, %2" : "=v"(hp) : "v"(a), "v"(b));
    float ra = a - __uint_as_float(hp << 16);
    float rb = b - __uint_as_float(hp & 0xFFFF0000u);
    asm("v_cvt_pk_bf16_f32 %0, %1, %2" : "=v"(lp) : "v"(ra), "v"(rb));
    return make_uint2(hp, lp);
}

__device__ __forceinline__ ushort bf16rne(float x) {
    unsigned b = __float_as_uint(x);
    b += 0x7FFFu + ((b >> 16) & 1u);
    return (ushort)(b >> 16);
}

// ---- Fourier features -> plane layout; k<64: sin_j, k>=64: cos_j ----
__device__ __forceinline__ void feats_stage(const float2* __restrict__ inp2,
                                            const float* __restrict__ fB,
                                            uint* buf, int t, int base) {
    int p = t & 31, jg = t >> 5;            // 16 j-groups x 4 features
    float2 xy = inp2[base + p];
    float s[4], c[4];
#pragma unroll
    for (int q = 0; q < 4; ++q) {
        int j = jg * 4 + q;
        float d = xy.x * fB[j] + xy.y * fB[64 + j];
        sincos_rev(d, &s[q], &c[q]);
    }
    uint2 s01 = packpair(s[0], s[1]), s23 = packpair(s[2], s[3]);
    uint2 c01 = packpair(c[0], c[1]), c23 = packpair(c[2], c[3]);
    uint* row = buf + p * LROW;
    *(uint2*)&row[jg * 2]      = make_uint2(s01.x, s23.x);
    *(uint2*)&row[32 + jg * 2] = make_uint2(c01.x, c23.x);
    *(uint2*)&row[64 + jg * 2] = make_uint2(s01.y, s23.y);
    *(uint2*)&row[96 + jg * 2] = make_uint2(c01.y, c23.y);
    __syncthreads();
}

// ---- 3-term split GEMM: rows 16w+(lq*4+r), points pt*16+lr, K=128 ----
__device__ __forceinline__ void gemm3(const uint* __restrict__ wp,
                                      const uint* buf, int lane, int wave,
                                      f32x4 acc[2]) {
    f32x4 z = {0.f, 0.f, 0.f, 0.f};
    acc[0] = z; acc[1] = z;
    int lq = lane >> 4, lr = lane & 15;
#pragma unroll 1
    for (int kt = 0; kt < 4; ++kt) {
        const uint4* wf = (const uint4*)wp + ((wave * 4 + kt) * 64 + lane) * 2;
        bf16x8 Ahi = asfrag(wf[0]);
        bf16x8 Alo = asfrag(wf[1]);
#pragma unroll
        for (int pt = 0; pt < 2; ++pt) {
            const uint* prow = buf + (pt * 16 + lr) * LROW + kt * 16 + lq * 4;
            bf16x8 Bhi = asfrag(*(const uint4*)prow);
            bf16x8 Blo = asfrag(*(const uint4*)(prow + 64));
            acc[pt] = mfma16(Ahi, Blo, acc[pt]);
            acc[pt] = mfma16(Alo, Bhi, acc[pt]);
            acc[pt] = mfma16(Ahi, Bhi, acc[pt]);
        }
    }
}

// ---- mid layer: y = tanh(W h + b), plane writes ----
__device__ __forceinline__ void mid_layer(const uint* __restrict__ wp,
                                          const float* __restrict__ bias,
                                          const uint* bin, uint* bout,
                                          int lane, int wave) {
    f32x4 acc[2];
    gemm3(wp, bin, lane, wave, acc);
    int lq = lane >> 4, lr = lane & 15;
    float4 bv = *(const float4*)&bias[wave * 16 + lq * 4];
#pragma unroll
    for (int pt = 0; pt < 2; ++pt) {
        float t0 = fast_tanh(acc[pt][0] + bv.x);
        float t1 = fast_tanh(acc[pt][1] + bv.y);
        float t2 = fast_tanh(acc[pt][2] + bv.z);
        float t3 = fast_tanh(acc[pt][3] + bv.w);
        uint2 q01 = packpair(t0, t1), q23 = packpair(t2, t3);
        uint* row = bout + (pt * 16 + lr) * LROW + wave * 8 + lq * 2;
        *(uint2*)&row[0]  = make_uint2(q01.x, q23.x);
        *(uint2*)&row[64] = make_uint2(q01.y, q23.y);
    }
}

// ================= prepack: split weights into frag-ready bf16 hi/lo ========
__global__ void prepack(const float* __restrict__ W0, const float* __restrict__ b0,
                        const float* __restrict__ W1, const float* __restrict__ W2,
                        const float* __restrict__ W3, uint* __restrict__ wpack) {
    int tid = blockIdx.x * 256 + threadIdx.x;
    if (tid < 8192) {
        int mat = tid >> 11, slot = tid & 2047;
        int m = slot >> 8, kt = (slot >> 6) & 3, l = slot & 63;
        int row = m * 16 + (l & 15), kb = kt * 32 + ((l >> 4) << 3);
        const float* W; int stride, coff;
        if (mat == 0)      { W = W0; stride = 130; coff = 2; }
        else if (mat == 1) { W = W1; stride = 128; coff = 0; }
        else if (mat == 2) { W = W2; stride = 128; coff = 0; }
        else               { W = W3; stride = 128; coff = 0; }
        uint hi[8], lo[8];
#pragma unroll
        for (int i = 0; i < 8; ++i) {
            float w = W[row * stride + coff + kb + i];
            ushort h = bf16rne(w);
            float hf = __uint_as_float((uint)h << 16);
            hi[i] = h; lo[i] = bf16rne(w - hf);
        }
        uint* dst = wpack + (uint)tid * 8;
        dst[0] = hi[0] | (hi[1] << 16); dst[1] = hi[2] | (hi[3] << 16);
        dst[2] = hi[4] | (hi[5] << 16); dst[3] = hi[6] | (hi[7] << 16);
        dst[4] = lo[0] | (lo[1] << 16); dst[5] = lo[2] | (lo[3] << 16);
        dst[6] = lo[4] | (lo[5] << 16); dst[7] = lo[6] | (lo[7] << 16);
    } else if (tid < 8320) {
        int row = tid - 8192;
        float4 h;
        h.x = b0[row]; h.y = W0[row * 130]; h.z = W0[row * 130 + 1]; h.w = 0.f;
        ((float4*)(wpack + HEADU))[row] = h;
    }
}

// ================= pass A: sum y^2 (hi-plane-only approx; std needs ~0.3%) ==
__global__ __launch_bounds__(BLOCK, 8) void pass_a(const float2* __restrict__ inp2,
                                                   const float* __restrict__ fB,
                                                   const uint* __restrict__ wpack,
                                                   float* __restrict__ ssq) {
    __shared__ __align__(16) uint buf0[TILE * LROW];
    __shared__ float red[8];
    int t = threadIdx.x;
    int lane = t & 63;
    int wave = __builtin_amdgcn_readfirstlane(t >> 6);
    int base = blockIdx.x * TILE;

    feats_stage(inp2, fB, buf0, t, base);

    f32x4 acc[2];
    f32x4 z = {0.f, 0.f, 0.f, 0.f};
    acc[0] = z; acc[1] = z;
    int lq = lane >> 4, lr = lane & 15;
#pragma unroll 1
    for (int kt = 0; kt < 4; ++kt) {
        const uint4* wf = (const uint4*)wpack + ((wave * 4 + kt) * 64 + lane) * 2;
        bf16x8 Ahi = asfrag(wf[0]);
#pragma unroll
        for (int pt = 0; pt < 2; ++pt) {
            const uint* prow = buf0 + (pt * 16 + lr) * LROW + kt * 16 + lq * 4;
            bf16x8 Bhi = asfrag(*(const uint4*)prow);
            acc[pt] = mfma16(Ahi, Bhi, acc[pt]);
        }
    }
    const float4* head = (const float4*)(wpack + HEADU);
    float4 hd[4];
#pragma unroll
    for (int r = 0; r < 4; ++r) hd[r] = head[wave * 16 + lq * 4 + r];
    float ss = 0.f;
#pragma unroll
    for (int pt = 0; pt < 2; ++pt) {
        float2 xy = inp2[base + pt * 16 + lr];
#pragma unroll
        for (int r = 0; r < 4; ++r) {
            float y = acc[pt][r] + (hd[r].x + hd[r].y * xy.x + hd[r].z * xy.y);
            ss = fmaf(y, y, ss);
        }
    }
#pragma unroll
    for (int off = 32; off > 0; off >>= 1) ss += __shfl_down(ss, off, 64);
    if (lane == 0) red[wave] = ss;
    __syncthreads();
    if (t == 0) {
        float s = 0.f;
#pragma unroll
        for (int w = 0; w < 8; ++w) s += red[w];
        atomicAdd(&ssq[blockIdx.x & (NSLOTS - 1)], s);   // native f32 atomic
    }
}

// ================= std finalize ============================================
__global__ void finalize_std(const float* __restrict__ ssq, float* __restrict__ stdp) {
    double s = 0.0;
    for (int i = 0; i < NSLOTS; ++i) s += (double)ssq[i];
    float power = (float)(s / 128000000.0);
    float v = 0.f;
    if (isfinite(power) && power > 1.1920929e-07f) v = sqrtf(power / 1000.0f);
    *stdp = v;
}

// ================= pass B: full fused forward ==============================
__global__ __launch_bounds__(BLOCK, 8) void pass_b(const float2* __restrict__ inp2,
                                                   const float* __restrict__ fB,
                                                   const uint* __restrict__ wpack,
                                                   const float* __restrict__ b1,
                                                   const float* __restrict__ b2,
                                                   const float* __restrict__ b3,
                                                   const float* __restrict__ W4,
                                                   const float* __restrict__ b4,
                                                   const float* __restrict__ stdp,
                                                   float* __restrict__ out) {
    __shared__ __align__(16) uint buf0[TILE * LROW];
    __shared__ __align__(16) uint buf1[TILE * LROW];
    __shared__ float pa[16][TILE][2];
    int t = threadIdx.x;
    int lane = t & 63;
    int wave = __builtin_amdgcn_readfirstlane(t >> 6);
    int base = blockIdx.x * TILE;

    feats_stage(inp2, fB, buf0, t, base);
    float stdv = *stdp;

    // layer 0: gemm + head + STE noise + tanh -> buf1 planes
    {
        f32x4 acc[2];
        gemm3(wpack, buf0, lane, wave, acc);
        int lq = lane >> 4, lr = lane & 15;
        const float4* head = (const float4*)(wpack + HEADU);
        float4 hd[4];
#pragma unroll
        for (int r = 0; r < 4; ++r) hd[r] = head[wave * 16 + lq * 4 + r];
#pragma unroll
        for (int pt = 0; pt < 2; ++pt) {
            float2 xy = inp2[base + pt * 16 + lr];
            unsigned pidx = (unsigned)(base + pt * 16 + lr);
            float tv[4];
#pragma unroll
            for (int r = 0; r < 4; ++r) {
                float yy = acc[pt][r] + (hd[r].x + hd[r].y * xy.x + hd[r].z * xy.y);
                unsigned row = (unsigned)(wave * 16 + lq * 4 + r);
                float nz = jax_normal_f(pidx * 128u + row);
                float yhw = yy + nz * stdv;
                float h = (yhw + yy) - yy;      // forward value of the STE expr
                tv[r] = fast_tanh(h);
            }
            uint2 q01 = packpair(tv[0], tv[1]), q23 = packpair(tv[2], tv[3]);
            uint* row = buf1 + (pt * 16 + lr) * LROW + wave * 8 + lq * 2;
            *(uint2*)&row[0]  = make_uint2(q01.x, q23.x);
            *(uint2*)&row[64] = make_uint2(q01.y, q23.y);
        }
    }
    __syncthreads();

    mid_layer(wpack + 16384, b1, buf1, buf0, lane, wave);
    __syncthreads();
    mid_layer(wpack + 32768, b2, buf0, buf1, lane, wave);
    __syncthreads();
    mid_layer(wpack + 49152, b3, buf1, buf0, lane, wave);
    __syncthreads();

    // layer 4: 128 -> 2 ; 16 f-groups x 32 points
    {
        int p = t & 31, g = t >> 5;
        const uint* row = &buf0[p * LROW];
        uint4 hh = *(const uint4*)&row[g * 4];
        uint4 ll = *(const uint4*)&row[64 + g * 4];
        float hv[8];
        hv[0] = __uint_as_float(hh.x << 16) + __uint_as_float(ll.x << 16);
        hv[1] = __uint_as_float(hh.x & 0xFFFF0000u) + __uint_as_float(ll.x & 0xFFFF0000u);
        hv[2] = __uint_as_float(hh.y << 16) + __uint_as_float(ll.y << 16);
        hv[3] = __uint_as_float(hh.y & 0xFFFF0000u) + __uint_as_float(ll.y & 0xFFFF0000u);
        hv[4] = __uint_as_float(hh.z << 16) + __uint_as_float(ll.z << 16);
        hv[5] = __uint_as_float(hh.z & 0xFFFF0000u) + __uint_as_float(ll.z & 0xFFFF0000u);
        hv[6] = __uint_as_float(hh.w << 16) + __uint_as_float(ll.w << 16);
        hv[7] = __uint_as_float(hh.w & 0xFFFF0000u) + __uint_as_float(ll.w & 0xFFFF0000u);
        float4 wA = *(const float4*)&W4[g * 8];
        float4 wB = *(const float4*)&W4[g * 8 + 4];
        float4 wC = *(const float4*)&W4[128 + g * 8];
        float4 wD = *(const float4*)&W4[128 + g * 8 + 4];
        float a0 = 0.f, a1 = 0.f;
        a0 = fmaf(hv[0], wA.x, a0); a0 = fmaf(hv[1], wA.y, a0);
        a0 = fmaf(hv[2], wA.z, a0); a0 = fmaf(hv[3], wA.w, a0);
        a0 = fmaf(hv[4], wB.x, a0); a0 = fmaf(hv[5], wB.y, a0);
        a0 = fmaf(hv[6], wB.z, a0); a0 = fmaf(hv[7], wB.w, a0);
        a1 = fmaf(hv[0], wC.x, a1); a1 = fmaf(hv[1], wC.y, a1);
        a1 = fmaf(hv[2], wC.z, a1); a1 = fmaf(hv[3], wC.w, a1);
        a1 = fmaf(hv[4], wD.x, a1); a1 = fmaf(hv[5], wD.y, a1);
        a1 = fmaf(hv[6], wD.z, a1); a1 = fmaf(hv[7], wD.w, a1);
        pa[g][p][0] = a0; pa[g][p][1] = a1;
    }
    __syncthreads();
    if (t < 64) {
        int p = t & 31, j = t >> 5;
        float r = b4[j];
#pragma unroll
        for (int g = 0; g < 16; ++g) r += pa[g][p][j];
        out[(base + p) * 2 + j] = r;
    }
}

extern "C" void kernel_launch(void* const* d_in, const int* in_sizes, int n_in,
                              void* d_out, int out_size, void* d_ws, size_t ws_size,
                              hipStream_t stream) {
    const float* inp = (const float*)d_in[0];
    const float* fB  = (const float*)d_in[1];
    const float* W0  = (const float*)d_in[2];
    const float* b0  = (const float*)d_in[3];
    const float* W1  = (const float*)d_in[4];
    const float* b1  = (const float*)d_in[5];
    const float* W2  = (const float*)d_in[6];
    const float* b2  = (const float*)d_in[7];
    const float* W3  = (const float*)d_in[8];
    const float* b3  = (const float*)d_in[9];
    const float* W4  = (const float*)d_in[10];
    const float* b4  = (const float*)d_in[11];
    float*  out  = (float*)d_out;
    float*  ssq  = (float*)d_ws;                         // NSLOTS floats
    float*  stdp = (float*)((char*)d_ws + NSLOTS * 4);   // then 1 float
    uint*   wpack = (uint*)((char*)d_ws + WS_WPACK_OFF); // frag-packed weights

    hipMemsetAsync(d_ws, 0, NSLOTS * 4 + 4, stream);
    prepack<<<33, 256, 0, stream>>>(W0, b0, W1, W2, W3, wpack);
    pass_a<<<NBLK, BLOCK, 0, stream>>>((const float2*)inp, fB, wpack, ssq);
    finalize_std<<<1, 1, 0, stream>>>(ssq, stdp);
    pass_b<<<NBLK, BLOCK, 0, stream>>>((const float2*)inp, fB, wpack,
                                       b1, b2, b3, W4, b4, stdp, out);
}